// Round 3
// baseline (241.648 us; speedup 1.0000x reference)
//
#include <hip/hip_runtime.h>

// EdgeLoss: mean |sobel_mag(gray(pred)) - sobel_mag(gray(target))|
// pred/target: (32, 3, 512, 512) fp32, output: scalar fp32.
// Memory-bound: 201 MB read once -> ~32 us floor at 6.3 TB/s.
//
// R3 -> R4: perf was invariant to occupancy (64%->41%) and staging MLP
// (VGPR 16->44) -> not latency-bound; phase-serialization bound. LDS version
// spends ~32us mem + ~20us LDS-pipe (128 scalar ds_read/thread) + ~18us VALU
// in barrier-separated phases. This version deletes LDS entirely: register
// vertical pipeline. Each wave owns a 256x8 strip; lane owns 4 cols; 3-row
// gray window (A/B/C) lives in registers; horizontal halo = 2 extra scalar
// loads/image/row (L1 hits); vertical halo = register rotation. No barriers,
// 1-row-ahead load pipeline, sched_barrier(0) pins load issue before Sobel.
//
// R4 -> R5: identical resubmit — R4 never ran (GPUAcquisitionTimeout).

#define BATCH 32
#define HH 512
#define WW 512
#define SROWS 8                 // output rows per wave
#define IMG ((size_t)HH * WW)

__global__ void zero_out_kernel(float* out) { out[0] = 0.0f; }

// gray = 0.299 r + 0.587 g + 0.114 b (same op order as R2/R3)
#define TOGRAY(d4, dl, dr, r4, g4, b4, rl, gl, bl, rr, gr, br) do {   \
    d4.x = 0.299f * r4.x + 0.587f * g4.x + 0.114f * b4.x;             \
    d4.y = 0.299f * r4.y + 0.587f * g4.y + 0.114f * b4.y;             \
    d4.z = 0.299f * r4.z + 0.587f * g4.z + 0.114f * b4.z;             \
    d4.w = 0.299f * r4.w + 0.587f * g4.w + 0.114f * b4.w;             \
    dl   = 0.299f * (rl) + 0.587f * (gl) + 0.114f * (bl);             \
    dr   = 0.299f * (rr) + 0.587f * (gr) + 0.114f * (br);             \
} while (0)

// Sobel magnitude, exact same expression structure as R2/R3:
// a* = row y-1, b* = row y, c* = row y+1 ; index 0=j-1, 1=j, 2=j+1
#define MAG(a0, a1, a2, b0, b2, c0, c1, c2)                            \
    ({ float ex_ = ((a2) - (a0)) + 2.0f * ((b2) - (b0)) + ((c2) - (c0)); \
       float ey_ = ((c0) - (a0)) + 2.0f * ((c1) - (a1)) + ((c2) - (a2)); \
       sqrtf(ex_ * ex_ + ey_ * ey_); })

__global__ __launch_bounds__(256) void edge_loss_kernel(
    const float* __restrict__ pred,
    const float* __restrict__ target,
    float* __restrict__ out)
{
    const int tid  = threadIdx.x;
    const int lane = tid & 63;
    const int wav  = tid >> 6;
    const int colhalf = blockIdx.x;              // 0..1
    const int band = blockIdx.y * 4 + wav;       // 0..63 (8-row bands)
    const int b    = blockIdx.z;

    const int y0 = band * SROWS;                 // first output row
    const int c0 = colhalf * 256 + lane * 4;     // first col of this lane

    const float* pb = pred   + (size_t)b * 3 * IMG;
    const float* tb = target + (size_t)b * 3 * IMG;

    // Horizontal halo: clamp the offset so the load is always in-bounds,
    // select 0 afterwards (no exec-mask dance, no speculation hazard).
    const bool okl = (c0 >= 1);
    const bool okr = (c0 <= WW - 5);
    const int  xlo = okl ? -1 : 0;
    const int  xro = okr ?  4 : 3;

    // ---- channel staging registers (reused every row) ----
    float4 cpr, cpg, cpb, ctr, ctg, ctb;
    float  cprl, cpgl, cpbl, cprr, cpgr, cpbr;
    float  ctrl_, ctgl, ctbl, ctrr, ctgr, ctbr;

#define LOADROW(gy_) do {                                              \
    const int gy = (gy_);                                              \
    if ((unsigned)gy < (unsigned)HH) {                                 \
        const float* rp = pb + (size_t)gy * WW + c0;                   \
        const float* rt = tb + (size_t)gy * WW + c0;                   \
        cpr = *(const float4*)(rp);                                    \
        cpg = *(const float4*)(rp + IMG);                              \
        cpb = *(const float4*)(rp + 2 * IMG);                          \
        ctr = *(const float4*)(rt);                                    \
        ctg = *(const float4*)(rt + IMG);                              \
        ctb = *(const float4*)(rt + 2 * IMG);                          \
        float al0 = rp[xlo], al1 = rp[IMG + xlo], al2 = rp[2 * IMG + xlo]; \
        float ar0 = rp[xro], ar1 = rp[IMG + xro], ar2 = rp[2 * IMG + xro]; \
        float bl0 = rt[xlo], bl1 = rt[IMG + xlo], bl2 = rt[2 * IMG + xlo]; \
        float br0 = rt[xro], br1 = rt[IMG + xro], br2 = rt[2 * IMG + xro]; \
        cprl = okl ? al0 : 0.f; cpgl = okl ? al1 : 0.f; cpbl = okl ? al2 : 0.f; \
        cprr = okr ? ar0 : 0.f; cpgr = okr ? ar1 : 0.f; cpbr = okr ? ar2 : 0.f; \
        ctrl_ = okl ? bl0 : 0.f; ctgl = okl ? bl1 : 0.f; ctbl = okl ? bl2 : 0.f; \
        ctrr = okr ? br0 : 0.f; ctgr = okr ? br1 : 0.f; ctbr = okr ? br2 : 0.f; \
    } else {                                                           \
        cpr = cpg = cpb = make_float4(0.f, 0.f, 0.f, 0.f);             \
        ctr = ctg = ctb = make_float4(0.f, 0.f, 0.f, 0.f);             \
        cprl = cpgl = cpbl = cprr = cpgr = cpbr = 0.f;                 \
        ctrl_ = ctgl = ctbl = ctrr = ctgr = ctbr = 0.f;                \
    }                                                                  \
} while (0)

#define GRAY_P(d4, dl, dr) TOGRAY(d4, dl, dr, cpr, cpg, cpb, cprl, cpgl, cpbl, cprr, cpgr, cpbr)
#define GRAY_T(d4, dl, dr) TOGRAY(d4, dl, dr, ctr, ctg, ctb, ctrl_, ctgl, ctbl, ctrr, ctgr, ctbr)

    // ---- gray pipeline state: rows A (y-1), B (y), C (y+1) ----
    float4 pA4, pB4, pC4, tA4, tB4, tC4;
    float  pAl, pAr, pBl, pBr, pCl, pCr;
    float  tAl, tAr, tBl, tBr, tCl, tCr;

    // prologue
    LOADROW(y0 - 1);
    GRAY_P(pA4, pAl, pAr);
    GRAY_T(tA4, tAl, tAr);
    LOADROW(y0);
    GRAY_P(pB4, pBl, pBr);
    GRAY_T(tB4, tBl, tBr);
    LOADROW(y0 + 1);

    float lsum = 0.0f;

    #pragma unroll
    for (int i = 0; i < SROWS; ++i) {
        // consume the row issued one iteration ago
        GRAY_P(pC4, pCl, pCr);
        GRAY_T(tC4, tCl, tCr);

        // issue next row's loads before the Sobel VALU work
        if (i < SROWS - 1) LOADROW(y0 + 2 + i);
        __builtin_amdgcn_sched_barrier(0);   // loads stay above the Sobel

        float ep, et;
        // j = 0
        ep = MAG(pAl,   pA4.x, pA4.y,  pBl,   pB4.y,  pCl,   pC4.x, pC4.y);
        et = MAG(tAl,   tA4.x, tA4.y,  tBl,   tB4.y,  tCl,   tC4.x, tC4.y);
        lsum += fabsf(ep - et);
        // j = 1
        ep = MAG(pA4.x, pA4.y, pA4.z,  pB4.x, pB4.z,  pC4.x, pC4.y, pC4.z);
        et = MAG(tA4.x, tA4.y, tA4.z,  tB4.x, tB4.z,  tC4.x, tC4.y, tC4.z);
        lsum += fabsf(ep - et);
        // j = 2
        ep = MAG(pA4.y, pA4.z, pA4.w,  pB4.y, pB4.w,  pC4.y, pC4.z, pC4.w);
        et = MAG(tA4.y, tA4.z, tA4.w,  tB4.y, tB4.w,  tC4.y, tC4.z, tC4.w);
        lsum += fabsf(ep - et);
        // j = 3
        ep = MAG(pA4.z, pA4.w, pAr,    pB4.z, pBr,    pC4.z, pC4.w, pCr);
        et = MAG(tA4.z, tA4.w, tAr,    tB4.z, tBr,    tC4.z, tC4.w, tCr);
        lsum += fabsf(ep - et);

        // rotate window (register renaming in the unrolled loop -> free)
        pA4 = pB4; pAl = pBl; pAr = pBr;
        pB4 = pC4; pBl = pCl; pBr = pCr;
        tA4 = tB4; tAl = tBl; tAr = tBr;
        tB4 = tC4; tBl = tCl; tBr = tCr;
    }

    // ---- reduce: wave shuffle -> one atomic per wave ----
    #pragma unroll
    for (int off = 32; off > 0; off >>= 1)
        lsum += __shfl_down(lsum, off, 64);

    if (lane == 0) {
        const float inv_n = 1.0f / ((float)BATCH * HH * WW);
        atomicAdd(out, lsum * inv_n);
    }
}

extern "C" void kernel_launch(void* const* d_in, const int* in_sizes, int n_in,
                              void* d_out, int out_size, void* d_ws, size_t ws_size,
                              hipStream_t stream) {
    const float* pred   = (const float*)d_in[0];
    const float* target = (const float*)d_in[1];
    float* out = (float*)d_out;

    // d_out is poisoned 0xAA before every timed launch -> zero it on-stream.
    zero_out_kernel<<<1, 1, 0, stream>>>(out);

    dim3 grid(2, 16, BATCH);   // colhalf x bandgroup(4 bands/block) x batch
    edge_loss_kernel<<<grid, 256, 0, stream>>>(pred, target, out);
}

// Round 5
// 241.077 us; speedup vs baseline: 1.0024x; 1.0024x over previous
//
#include <hip/hip_runtime.h>

// EdgeLoss: mean |sobel_mag(gray(pred)) - sobel_mag(gray(target))|
// pred/target: (32, 3, 512, 512) fp32, output: scalar fp32.
//
// R5 post-mortem: register pipeline was issue-after-wait (vmcnt(0) per row,
// zero lookahead) + 12 scalar halo loads/row -> latency-serialized, 102us,
// VALUBusy 14.6%. L3-resident dispatches (FETCH=131KB) ran at the SAME
// speed -> pure latency-structure bound, not BW.
//
// R6: full-row waves (512 cols / 64 lanes = 8 cols/lane, 2 float4 per
// plane). Horizontal halo = neighbor lane's gray via __shfl (lane 0/63 =
// image border = 0) -> zero scalar loads. Double-buffered staging register
// sets X/Y: issue row i+2's 12 float4 loads BEFORE consuming row i+1 ->
// compiler emits counted vmcnt(12) waits, 12KB/wave in flight steady-state,
// 96KB/CU >> 9KB needed to saturate HBM. No LDS, no barriers.
// VALU floor ~4us, HBM floor ~32-40us (fetch 1.25x for 10/8 halo rows).
//
// R7: identical resubmit — R6 never ran (GPUAcquisitionTimeout).

#define BATCH 32
#define HH 512
#define WW 512
#define S 8                     // output rows per wave
#define IMG ((size_t)HH * WW)

__global__ void zero_out_kernel(float* out) { out[0] = 0.0f; }

// Sobel magnitude, same expression structure as R2..R5 (all passed):
// a* = row y-1, b* = row y, c* = row y+1 ; 0=j-1, 1=j, 2=j+1
#define MAG(a0, a1, a2, b0, b2, c0, c1, c2)                              \
    ({ float ex_ = ((a2) - (a0)) + 2.0f * ((b2) - (b0)) + ((c2) - (c0)); \
       float ey_ = ((c0) - (a0)) + 2.0f * ((c1) - (a1)) + ((c2) - (a2)); \
       sqrtf(ex_ * ex_ + ey_ * ey_); })

// Issue 12 independent float4 loads into staging set P (P = X or Y).
// Branch is wave-uniform (gy depends only on band). sched_barrier(0) pins
// the loads above everything that follows (no sinking past the consumer).
#define LOADSET(P, gy_) do {                                           \
    const int gy__ = (gy_);                                            \
    if ((unsigned)gy__ < (unsigned)HH) {                               \
        const float* rp__ = pbase + (size_t)gy__ * WW + cx;            \
        const float* rt__ = tbase + (size_t)gy__ * WW + cx;            \
        P##pr0 = *(const float4*)(rp__);                               \
        P##pr1 = *(const float4*)(rp__ + 4);                           \
        P##pg0 = *(const float4*)(rp__ + IMG);                         \
        P##pg1 = *(const float4*)(rp__ + IMG + 4);                     \
        P##pb0 = *(const float4*)(rp__ + 2 * IMG);                     \
        P##pb1 = *(const float4*)(rp__ + 2 * IMG + 4);                 \
        P##tr0 = *(const float4*)(rt__);                               \
        P##tr1 = *(const float4*)(rt__ + 4);                           \
        P##tg0 = *(const float4*)(rt__ + IMG);                         \
        P##tg1 = *(const float4*)(rt__ + IMG + 4);                     \
        P##tb0 = *(const float4*)(rt__ + 2 * IMG);                     \
        P##tb1 = *(const float4*)(rt__ + 2 * IMG + 4);                 \
    } else {                                                           \
        const float4 z__ = make_float4(0.f, 0.f, 0.f, 0.f);            \
        P##pr0 = z__; P##pr1 = z__; P##pg0 = z__; P##pg1 = z__;        \
        P##pb0 = z__; P##pb1 = z__; P##tr0 = z__; P##tr1 = z__;        \
        P##tg0 = z__; P##tg1 = z__; P##tb0 = z__; P##tb1 = z__;        \
    }                                                                  \
    __builtin_amdgcn_sched_barrier(0);                                 \
} while (0)

// Convert staging set P into gray row R (8 px/lane per image) + shfl halos.
#define GRAYSET(R, P) do {                                                  \
    R##p0 = 0.299f * P##pr0.x + 0.587f * P##pg0.x + 0.114f * P##pb0.x;      \
    R##p1 = 0.299f * P##pr0.y + 0.587f * P##pg0.y + 0.114f * P##pb0.y;      \
    R##p2 = 0.299f * P##pr0.z + 0.587f * P##pg0.z + 0.114f * P##pb0.z;      \
    R##p3 = 0.299f * P##pr0.w + 0.587f * P##pg0.w + 0.114f * P##pb0.w;      \
    R##p4 = 0.299f * P##pr1.x + 0.587f * P##pg1.x + 0.114f * P##pb1.x;      \
    R##p5 = 0.299f * P##pr1.y + 0.587f * P##pg1.y + 0.114f * P##pb1.y;      \
    R##p6 = 0.299f * P##pr1.z + 0.587f * P##pg1.z + 0.114f * P##pb1.z;      \
    R##p7 = 0.299f * P##pr1.w + 0.587f * P##pg1.w + 0.114f * P##pb1.w;      \
    R##t0 = 0.299f * P##tr0.x + 0.587f * P##tg0.x + 0.114f * P##tb0.x;      \
    R##t1 = 0.299f * P##tr0.y + 0.587f * P##tg0.y + 0.114f * P##tb0.y;      \
    R##t2 = 0.299f * P##tr0.z + 0.587f * P##tg0.z + 0.114f * P##tb0.z;      \
    R##t3 = 0.299f * P##tr0.w + 0.587f * P##tg0.w + 0.114f * P##tb0.w;      \
    R##t4 = 0.299f * P##tr1.x + 0.587f * P##tg1.x + 0.114f * P##tb1.x;      \
    R##t5 = 0.299f * P##tr1.y + 0.587f * P##tg1.y + 0.114f * P##tb1.y;      \
    R##t6 = 0.299f * P##tr1.z + 0.587f * P##tg1.z + 0.114f * P##tb1.z;      \
    R##t7 = 0.299f * P##tr1.w + 0.587f * P##tg1.w + 0.114f * P##tb1.w;      \
    { float sl_ = __shfl_up(R##p7, 1, 64);                                  \
      float sr_ = __shfl_down(R##p0, 1, 64);                                \
      R##pl = (lane == 0)  ? 0.f : sl_;                                     \
      R##pr = (lane == 63) ? 0.f : sr_;                                     \
      float tl_ = __shfl_up(R##t7, 1, 64);                                  \
      float tr_ = __shfl_down(R##t0, 1, 64);                                \
      R##tl = (lane == 0)  ? 0.f : tl_;                                     \
      R##tr = (lane == 63) ? 0.f : tr_; }                                   \
} while (0)

#define SOBELROW() do {                                              \
    float ep_, et_;                                                  \
    ep_ = MAG(Apl, Ap0, Ap1,  Bpl, Bp1,  Cpl, Cp0, Cp1);             \
    et_ = MAG(Atl, At0, At1,  Btl, Bt1,  Ctl, Ct0, Ct1);             \
    lsum += fabsf(ep_ - et_);                                        \
    ep_ = MAG(Ap0, Ap1, Ap2,  Bp0, Bp2,  Cp0, Cp1, Cp2);             \
    et_ = MAG(At0, At1, At2,  Bt0, Bt2,  Ct0, Ct1, Ct2);             \
    lsum += fabsf(ep_ - et_);                                        \
    ep_ = MAG(Ap1, Ap2, Ap3,  Bp1, Bp3,  Cp1, Cp2, Cp3);             \
    et_ = MAG(At1, At2, At3,  Bt1, Bt3,  Ct1, Ct2, Ct3);             \
    lsum += fabsf(ep_ - et_);                                        \
    ep_ = MAG(Ap2, Ap3, Ap4,  Bp2, Bp4,  Cp2, Cp3, Cp4);             \
    et_ = MAG(At2, At3, At4,  Bt2, Bt4,  Ct2, Ct3, Ct4);             \
    lsum += fabsf(ep_ - et_);                                        \
    ep_ = MAG(Ap3, Ap4, Ap5,  Bp3, Bp5,  Cp3, Cp4, Cp5);             \
    et_ = MAG(At3, At4, At5,  Bt3, Bt5,  Ct3, Ct4, Ct5);             \
    lsum += fabsf(ep_ - et_);                                        \
    ep_ = MAG(Ap4, Ap5, Ap6,  Bp4, Bp6,  Cp4, Cp5, Cp6);             \
    et_ = MAG(At4, At5, At6,  Bt4, Bt6,  Ct4, Ct5, Ct6);             \
    lsum += fabsf(ep_ - et_);                                        \
    ep_ = MAG(Ap5, Ap6, Ap7,  Bp5, Bp7,  Cp5, Cp6, Cp7);             \
    et_ = MAG(At5, At6, At7,  Bt5, Bt7,  Ct5, Ct6, Ct7);             \
    lsum += fabsf(ep_ - et_);                                        \
    ep_ = MAG(Ap6, Ap7, Apr,  Bp6, Bpr,  Cp6, Cp7, Cpr);             \
    et_ = MAG(At6, At7, Atr,  Bt6, Btr,  Ct6, Ct7, Ctr);             \
    lsum += fabsf(ep_ - et_);                                        \
} while (0)

#define ROTATE() do {                                                \
    Ap0=Bp0; Ap1=Bp1; Ap2=Bp2; Ap3=Bp3; Ap4=Bp4; Ap5=Bp5; Ap6=Bp6; Ap7=Bp7; \
    Apl=Bpl; Apr=Bpr;                                                \
    At0=Bt0; At1=Bt1; At2=Bt2; At3=Bt3; At4=Bt4; At5=Bt5; At6=Bt6; At7=Bt7; \
    Atl=Btl; Atr=Btr;                                                \
    Bp0=Cp0; Bp1=Cp1; Bp2=Cp2; Bp3=Cp3; Bp4=Cp4; Bp5=Cp5; Bp6=Cp6; Bp7=Cp7; \
    Bpl=Cpl; Bpr=Cpr;                                                \
    Bt0=Ct0; Bt1=Ct1; Bt2=Ct2; Bt3=Ct3; Bt4=Ct4; Bt5=Ct5; Bt6=Ct6; Bt7=Ct7; \
    Btl=Ctl; Btr=Ctr;                                                \
} while (0)

__global__ __launch_bounds__(256) void edge_loss_kernel(
    const float* __restrict__ pred,
    const float* __restrict__ target,
    float* __restrict__ out)
{
    const int tid  = threadIdx.x;
    const int lane = tid & 63;
    const int wav  = tid >> 6;
    const int band = blockIdx.x * 4 + wav;   // 0..63 (8-row bands)
    const int b    = blockIdx.y;
    const int y0   = band * S;
    const int cx   = lane * 8;               // first col of this lane

    const float* pbase = pred   + (size_t)b * 3 * IMG;
    const float* tbase = target + (size_t)b * 3 * IMG;

    // ---- staging register sets (double buffer), 12 float4 each ----
    float4 Xpr0, Xpr1, Xpg0, Xpg1, Xpb0, Xpb1;
    float4 Xtr0, Xtr1, Xtg0, Xtg1, Xtb0, Xtb1;
    float4 Ypr0, Ypr1, Ypg0, Ypg1, Ypb0, Ypb1;
    float4 Ytr0, Ytr1, Ytg0, Ytg1, Ytb0, Ytb1;

    // ---- gray window rows A (y-1), B (y), C (y+1): 8 px + 2 halos x 2 img ----
    float Ap0,Ap1,Ap2,Ap3,Ap4,Ap5,Ap6,Ap7, Apl,Apr;
    float At0,At1,At2,At3,At4,At5,At6,At7, Atl,Atr;
    float Bp0,Bp1,Bp2,Bp3,Bp4,Bp5,Bp6,Bp7, Bpl,Bpr;
    float Bt0,Bt1,Bt2,Bt3,Bt4,Bt5,Bt6,Bt7, Btl,Btr;
    float Cp0,Cp1,Cp2,Cp3,Cp4,Cp5,Cp6,Cp7, Cpl,Cpr;
    float Ct0,Ct1,Ct2,Ct3,Ct4,Ct5,Ct6,Ct7, Ctl,Ctr;

    // ---- prologue: X<-row y0-1, Y<-row y0, consume X, X<-row y0+1, consume Y
    LOADSET(X, y0 - 1);
    LOADSET(Y, y0);
    GRAYSET(A, X);               // waits on X only (Y's 12 loads in flight)
    LOADSET(X, y0 + 1);
    GRAYSET(B, Y);               // waits on Y only (X's 12 loads in flight)

    float lsum = 0.0f;

    // ---- steady state: issue row y0+2+i, consume row y0+1+i, Sobel row y0+i
    #pragma unroll
    for (int i = 0; i < S; ++i) {
        if (i & 1) {
            if (i < S - 1) LOADSET(X, y0 + 2 + i);
            GRAYSET(C, Y);       // row y0+1+i, loaded last iteration
        } else {
            if (i < S - 1) LOADSET(Y, y0 + 2 + i);
            GRAYSET(C, X);
        }
        SOBELROW();
        ROTATE();
    }

    // ---- reduce: wave shuffle -> one atomic per wave ----
    #pragma unroll
    for (int off = 32; off > 0; off >>= 1)
        lsum += __shfl_down(lsum, off, 64);

    if (lane == 0) {
        const float inv_n = 1.0f / ((float)BATCH * HH * WW);
        atomicAdd(out, lsum * inv_n);
    }
}

extern "C" void kernel_launch(void* const* d_in, const int* in_sizes, int n_in,
                              void* d_out, int out_size, void* d_ws, size_t ws_size,
                              hipStream_t stream) {
    const float* pred   = (const float*)d_in[0];
    const float* target = (const float*)d_in[1];
    float* out = (float*)d_out;

    // d_out is poisoned 0xAA before every timed launch -> zero it on-stream.
    zero_out_kernel<<<1, 1, 0, stream>>>(out);

    // 16 band-groups (4 waves/block x 4 bands) x 32 images = 512 blocks,
    // 2048 waves total = 8 waves/CU.
    dim3 grid(16, BATCH, 1);
    edge_loss_kernel<<<grid, 256, 0, stream>>>(pred, target, out);
}